// Round 2
// baseline (199.194 us; speedup 1.0000x reference)
//
#include <hip/hip_runtime.h>

typedef unsigned long long ull;

#define HH 256
#define WW 256
#define PLANE (HH*WW)
#define TILE_R 16            // was 32: 512 blocks -> 2 independent blocks/CU (exchange+convoy overlap)
#define TILE_C 64
#define TT 8
#define ER (TILE_R + 2*TT)   // 32 ext rows
#define EC (TILE_C + 2*TT)   // 80 ext cols (uv-pairs per row)
#define NCP (EC/2)           // 40 col-pairs per row
#define NRG 8                // row groups
#define RPT (ER/NRG)         // 4 rows per thread
#define NTHR 320             // = NCP*NRG, zero idle threads (5 waves/block, 10 waves/CU)
#define STRIDE 164           // row stride in floats; 164 % 32 == 4, 16B-aligned
#define LSZ (4 + ER*STRIDE + 4)   // floats: front pad + tile + end pad (~21 KB/buffer)

#define RING_OFS (2u*1024u*1024u)   // float offset of ring slot 1 (8 MB)
#define FLAG_OFS (3584u*1024u)      // float offset of flag array (14 MB; 12-16 MB gap is unused)
#define RIMG (HH*(WW/2)*4)          // floats per interleaved ring image (131072)
#define NBLK 512

// one Jacobi step over this thread's 2 cols x RPT rows; own-row centers carried in Mreg
__device__ __forceinline__ void hs_step(
    const float* __restrict__ rbuf, float* __restrict__ wbuf,
    int fb, int rm, int r0, int rN,
    float4* __restrict__ Mreg,
    const float2* __restrict__ ca, const float2* __restrict__ cb,
    const float2* __restrict__ cc, const float2* __restrict__ cd,
    const float2* __restrict__ ce)
{
    const float* qb = rbuf + fb;

    // edge columns for rows rm, r0..r0+RPT-1, rN + boundary-row centers (LDS)
    float2 L[RPT+2], R[RPT+2];
    const float* p0 = qb + STRIDE*rm;
    const float* pN = qb + STRIDE*rN;
    L[0] = *(const float2*)(p0 - 2);  R[0] = *(const float2*)(p0 + 4);
    #pragma unroll
    for (int j = 0; j < RPT; ++j) {
        const float* pr = qb + STRIDE*(r0 + j);
        L[j+1] = *(const float2*)(pr - 2);
        R[j+1] = *(const float2*)(pr + 4);
    }
    L[RPT+1] = *(const float2*)(pN - 2);  R[RPT+1] = *(const float2*)(pN + 4);
    float4 Mb0 = *(const float4*)(p0);
    float4 MbN = *(const float4*)(pN);

    // horizontal [1,2,1] sums
    float2 hu[RPT+2], hv[RPT+2];
    hu[0] = make_float2(fmaf(2.f,Mb0.x,L[0].x)+Mb0.z, fmaf(2.f,Mb0.z,Mb0.x)+R[0].x);
    hv[0] = make_float2(fmaf(2.f,Mb0.y,L[0].y)+Mb0.w, fmaf(2.f,Mb0.w,Mb0.y)+R[0].y);
    #pragma unroll
    for (int j = 0; j < RPT; ++j) {
        float4 Mc = Mreg[j];
        hu[j+1] = make_float2(fmaf(2.f,Mc.x,L[j+1].x)+Mc.z, fmaf(2.f,Mc.z,Mc.x)+R[j+1].x);
        hv[j+1] = make_float2(fmaf(2.f,Mc.y,L[j+1].y)+Mc.w, fmaf(2.f,Mc.w,Mc.y)+R[j+1].y);
    }
    hu[RPT+1] = make_float2(fmaf(2.f,MbN.x,L[RPT+1].x)+MbN.z, fmaf(2.f,MbN.z,MbN.x)+R[RPT+1].x);
    hv[RPT+1] = make_float2(fmaf(2.f,MbN.y,L[RPT+1].y)+MbN.w, fmaf(2.f,MbN.w,MbN.y)+R[RPT+1].y);

    // vertical combine + coupled update + write + register carry
    #pragma unroll
    for (int j = 0; j < RPT; ++j) {
        float4 Mc = Mreg[j];
        float tux = fmaf(-4.f, Mc.x, fmaf(2.f, hu[j+1].x, hu[j].x) + hu[j+2].x);
        float tuy = fmaf(-4.f, Mc.z, fmaf(2.f, hu[j+1].y, hu[j].y) + hu[j+2].y);
        float tvx = fmaf(-4.f, Mc.y, fmaf(2.f, hv[j+1].x, hv[j].x) + hv[j+2].x);
        float tvy = fmaf(-4.f, Mc.w, fmaf(2.f, hv[j+1].y, hv[j].y) + hv[j+2].y);
        float2 un, vn;
        un.x = fmaf(ca[j].x, tux, -fmaf(cb[j].x, tvx, cc[j].x));
        un.y = fmaf(ca[j].y, tuy, -fmaf(cb[j].y, tvy, cc[j].y));
        vn.x = fmaf(cd[j].x, tvx, -fmaf(cb[j].x, tux, ce[j].x));
        vn.y = fmaf(cd[j].y, tvy, -fmaf(cb[j].y, tuy, ce[j].y));
        float4 nv = make_float4(un.x, vn.x, un.y, vn.y);
        *(float4*)(wbuf + STRIDE*(r0 + j) + fb) = nv;
        Mreg[j] = nv;
    }
}

// __launch_bounds__(320,4): caps VGPR at 128 -> >=16 waves/CU by regs; LDS 42KB -> 3 blocks/CU.
// Residency capacity >= 3 blocks/CU x 256 CU = 768 >= 512 blocks: all co-resident (flag sync safe).
__global__ __launch_bounds__(NTHR, 4)
void hs_mega(const float* __restrict__ x,     // (8,3,256,256): It, Ix, Iy
             const float* __restrict__ est,   // (8,2,256,256): u0, v0
             float* __restrict__ out,         // (8,2,256,256)
             float* __restrict__ ws)          // rings (double-buffered) + flags
{
    __shared__ __align__(16) float s0[LSZ];
    __shared__ __align__(16) float s1[LSZ];

    const int img = blockIdx.x, cs = blockIdx.y, rb = blockIdx.z;
    const int tid = threadIdx.x;
    const int er0 = rb*TILE_R - TT;
    const int ec0 = cs*TILE_C - TT;
    const int blin = (img*4 + cs)*16 + rb;     // 0..511
    unsigned* flags = (unsigned*)(ws + FLAG_OFS);

    // neighbor block id for the 8 poller threads (same image, 8-neighborhood)
    int nb = -1;
    if (tid < 8) {
        int t = (tid < 4) ? tid : tid + 1;     // skip (0,0)
        int dr = t/3 - 1, dc = t%3 - 1;
        int nrb = rb + dr, ncs = cs + dc;
        if (nrb >= 0 && nrb < 16 && ncs >= 0 && ncs < 4)
            nb = (img*4 + ncs)*16 + nrb;
    }

    // ---- per-thread sweep geometry: 2 adjacent uv-cols x RPT rows ----
    const int cp = tid % NCP;          // 0..39
    const int rg = tid / NCP;          // 0..7
    const int r0 = rg * RPT;
    const int fb = 4 + 4*cp;           // float index of col pair in row 0
    const int rm = (r0 == 0) ? 0 : r0 - 1;             // clamp: feeds d=0 ring only
    const int rN = (r0 + RPT > ER-1) ? ER-1 : r0+RPT;  // clamp: feeds d=0 ring only

    // ---- per-pixel update coefficients, computed ONCE, live in registers ----
    // OOB pixels get all-zero coeffs -> update writes exact 0 -> matches reference zero-pad.
    float2 ca[RPT], cb[RPT], cc[RPT], cd[RPT], ce[RPT];
    {
        const float* __restrict__ xit = x + img*3*PLANE;
        const float* __restrict__ xix = xit + PLANE;
        const float* __restrict__ xiy = xix + PLANE;
        #pragma unroll
        for (int i = 0; i < RPT; ++i) {
            int gr = er0 + r0 + i;
            #pragma unroll
            for (int j = 0; j < 2; ++j) {
                int gc = ec0 + 2*cp + j;
                float A=0.f, B=0.f, C=0.f, D=0.f, E=0.f;
                if (gr >= 0 && gr < HH && gc >= 0 && gc < WW) {
                    int q = gr*WW + gc;
                    float it = xit[q], ix = xix[q], iy = xiy[q];
                    float rd = 1.0f / (1.0f + ix*ix + iy*iy);
                    const float s12 = 1.0f/12.0f;
                    A = (1.0f - ix*ix*rd) * s12;
                    B = (ix*iy*rd) * s12;
                    C = ix*it*rd;
                    D = (1.0f - iy*iy*rd) * s12;
                    E = iy*it*rd;
                }
                if (j == 0) { ca[i].x=A; cb[i].x=B; cc[i].x=C; cd[i].x=D; ce[i].x=E; }
                else        { ca[i].y=A; cb[i].y=B; cc[i].y=C; cd[i].y=D; ce[i].y=E; }
            }
        }
    }

    // ---- initial full ext-tile stage from est (interleave on the fly) ----
    {
        const float* __restrict__ eu = est + img*2*PLANE;
        const float* __restrict__ ev = eu + PLANE;
        for (int k = tid; k < ER*NCP; k += NTHR) {           // 1280 chunks, 4 iters
            int r = k / NCP, c = k - r*NCP;
            int gr = er0 + r, gc = ec0 + 2*c;
            float2 uu = make_float2(0.f,0.f), vv = make_float2(0.f,0.f);
            if (gr >= 0 && gr < HH && gc >= 0 && gc < WW) {  // gc even -> pair in-bounds
                uu = *(const float2*)(eu + gr*WW + gc);
                vv = *(const float2*)(ev + gr*WW + gc);
            }
            *(float4*)(s0 + 4 + STRIDE*r + 4*c) = make_float4(uu.x, vv.x, uu.y, vv.y);
        }
    }
    __syncthreads();

    // own-row center values, carried in registers; refreshed after each restage
    float4 Mreg[RPT];
    #pragma unroll
    for (int j = 0; j < RPT; ++j)
        Mreg[j] = *(const float4*)(s0 + STRIDE*(r0 + j) + fb);

    for (int p = 0; p < 13; ++p) {
        // ---- steps fully unrolled, compile-time buffer parity, 1 barrier each ----
        if (p < 12) {
            #pragma unroll
            for (int q = 0; q < 4; ++q) {
                hs_step(s0, s1, fb, rm, r0, rN, Mreg, ca, cb, cc, cd, ce);
                __syncthreads();
                hs_step(s1, s0, fb, rm, r0, rN, Mreg, ca, cb, cc, cd, ce);
                __syncthreads();
            }
        } else {
            #pragma unroll
            for (int q = 0; q < 2; ++q) {
                hs_step(s0, s1, fb, rm, r0, rN, Mreg, ca, cb, cc, cd, ce);
                __syncthreads();
                hs_step(s1, s0, fb, rm, r0, rN, Mreg, ca, cb, cc, cd, ce);
                __syncthreads();
            }
        }
        // result now in s0

        if (p < 12) {
            float* ring = ws + (unsigned)(p & 1) * RING_OFS + img*RIMG;

            // ---- write ring: with TILE_R=16 the 8-deep border is the WHOLE inner tile ----
            // 512 chunks: r = 0..15, c2 = 0..31 (inner pair-cols)
            for (int k = tid; k < 512; k += NTHR) {
                int r = k >> 5, c2 = k & 31;
                const float* sp = s0 + 4 + STRIDE*(r + TT) + 4*(c2 + 4);  // ext col pair = c2+4
                float* gp = ring + ((rb*TILE_R + r)*(WW/2) + cs*(TILE_C/2) + c2)*4;
                __hip_atomic_store((ull*)gp,     *(const ull*)sp,       __ATOMIC_RELAXED, __HIP_MEMORY_SCOPE_AGENT);
                __hip_atomic_store((ull*)gp + 1, *(const ull*)(sp + 2), __ATOMIC_RELAXED, __HIP_MEMORY_SCOPE_AGENT);
            }
            asm volatile("s_waitcnt vmcnt(0)" ::: "memory");   // per-wave drain of ring stores
            __syncthreads();
            if (tid == 0)
                __hip_atomic_store(&flags[p*NBLK + blin], 0x5eed0100u + (unsigned)p,
                                   __ATOMIC_RELAXED, __HIP_MEMORY_SCOPE_AGENT);
            asm volatile("" ::: "memory");
            if (tid < 8 && nb >= 0) {
                const unsigned tgt = 0x5eed0100u + (unsigned)p;
                while (__hip_atomic_load(&flags[p*NBLK + nb],
                                         __ATOMIC_RELAXED, __HIP_MEMORY_SCOPE_AGENT) != tgt)
                    __builtin_amdgcn_s_sleep(1);
            }
            __syncthreads();

            // ---- restage ext halo frame from neighbors (coherent 8B loads) ----
            // 768 chunks: rows 0..7 x 40 pairs, rows 24..31 x 40, rows 8..23 x {0..3,36..39}
            for (int k = tid; k < 768; k += NTHR) {
                int m = k; int r, c2;
                if (m < 320)      { r = m / 40;              c2 = m - (m/40)*40; }
                else if (m < 640) { int mm = m-320; r = 24 + mm/40; c2 = mm - (mm/40)*40; }
                else { int mm = m - 640; r = 8 + (mm >> 3); int t = mm & 7; c2 = (t < 4) ? t : 32 + t; }
                int gr = er0 + r, gc2 = cs*(TILE_C/2) - 4 + c2;
                ull v0 = 0, v1 = 0;
                if (gr >= 0 && gr < HH && gc2 >= 0 && gc2 < WW/2) {
                    const float* gp = ring + (gr*(WW/2) + gc2)*4;
                    v0 = __hip_atomic_load((const ull*)gp,     __ATOMIC_RELAXED, __HIP_MEMORY_SCOPE_AGENT);
                    v1 = __hip_atomic_load((const ull*)gp + 1, __ATOMIC_RELAXED, __HIP_MEMORY_SCOPE_AGENT);
                }
                float* sp = s0 + 4 + STRIDE*r + 4*c2;
                *(ull*)sp = v0;
                *(ull*)(sp + 2) = v1;
            }
            __syncthreads();

            // refresh carried centers (restage rewrote halo regions of s0)
            #pragma unroll
            for (int j = 0; j < RPT; ++j)
                Mreg[j] = *(const float4*)(s0 + STRIDE*(r0 + j) + fb);
        }
    }

    // ---- final: de-interleave inner tile to planar out ----
    {
        float* ou = out + img*2*PLANE;
        float* ov = ou + PLANE;
        for (int k = tid; k < 512; k += NTHR) {
            int r = k >> 5, c2 = k & 31;
            float4 V = *(const float4*)(s0 + 4 + STRIDE*(r + TT) + 4*(c2 + 4));
            int q = (rb*TILE_R + r)*WW + cs*TILE_C + 2*c2;
            *(float2*)(ou + q) = make_float2(V.x, V.z);
            *(float2*)(ov + q) = make_float2(V.y, V.w);
        }
    }
}

extern "C" void kernel_launch(void* const* d_in, const int* in_sizes, int n_in,
                              void* d_out, int out_size, void* d_ws, size_t ws_size,
                              hipStream_t stream) {
    const float* x   = (const float*)d_in[0];   // (8,3,256,256) fp32
    const float* est = (const float*)d_in[1];   // (8,2,256,256) fp32
    float* out = (float*)d_out;
    float* ws  = (float*)d_ws;                  // ring slot0 @0, slot1 @8MB, flags @14MB
                                                // flags 0xAA-poisoned each launch: != MAGIC, no reset needed

    dim3 grid(8, WW/TILE_C, HH/TILE_R);         // 512 blocks -> 2/CU, all co-resident (42KB LDS, <=128 VGPR)
    dim3 blk(NTHR);
    hs_mega<<<grid, blk, 0, stream>>>(x, est, out, ws);
}

// Round 3
// 178.271 us; speedup vs baseline: 1.1174x; 1.1174x over previous
//
#include <hip/hip_runtime.h>

typedef unsigned long long ull;

#define HH 256
#define WW 256
#define PLANE (HH*WW)
#define TILE_R 32
#define TILE_C 64
#define TT 8
#define ER (TILE_R + 2*TT)   // 48 ext rows
#define EC (TILE_C + 2*TT)   // 80 ext cols
#define NCP (EC/2)           // 40 col-pairs per row
#define NRG 8                // row groups = waves (wave w owns rows w*RPT..w*RPT+5, lanes 0..39 = colpair)
#define RPT (ER/NRG)         // 6 rows per thread
#define NTHR 512             // 8 waves; lanes 40..63 idle in compute, active in staging loops
#define STRIDE 164           // row stride in floats, 16B-aligned
#define LSZ (4 + ER*STRIDE + 4)   // front pad + tile + end pad (~31.5 KB/buffer)

#define RING_OFS (2u*1024u*1024u)   // float offset of ring slot 1 (8 MB)
#define FLAG_OFS (4u*1024u*1024u)   // float offset of flag array (16 MB)
#define RIMG (HH*(WW/2)*4)          // floats per interleaved ring image (131072)
#define NBLK 256

// DPP cross-lane: VALU pipe, replaces LDS L/R edge reads.
// wave_shr:1 (0x138): lane n receives lane n-1 (LLVM AMDGPUAtomicOptimizer scan convention).
// wave_shl:1 (0x130): lane n receives lane n+1.
// bound_ctrl=true: out-of-range / EXEC-disabled source lanes give 0 -> lands only on ext-edge
// columns (ring-0, decays before each exchange), same contract as the old pad-garbage reads.
__device__ __forceinline__ float dpp_prev(float v) {
    return __int_as_float(__builtin_amdgcn_update_dpp(0, __float_as_int(v), 0x138, 0xF, 0xF, true));
}
__device__ __forceinline__ float dpp_next(float v) {
    return __int_as_float(__builtin_amdgcn_update_dpp(0, __float_as_int(v), 0x130, 0xF, 0xF, true));
}

// horizontal [1,2,1] sums for one row held in a float4 (u0,v0,u1,v1); L/R via DPP.
// L = left pair's (u1,v1) = lane-1's (.z,.w); R = right pair's (u0,v0) = lane+1's (.x,.y).
__device__ __forceinline__ void hsum(const float4 M, float2& hu, float2& hv) {
    float Lz = dpp_prev(M.z), Lw = dpp_prev(M.w);
    float Rx = dpp_next(M.x), Ry = dpp_next(M.y);
    hu = make_float2(fmaf(2.f, M.x, Lz) + M.z, fmaf(2.f, M.z, M.x) + Rx);
    hv = make_float2(fmaf(2.f, M.y, Lw) + M.w, fmaf(2.f, M.w, M.y) + Ry);
}

// one Jacobi step: LDS = 2 b128 boundary reads + 2 (or 6 on fullwb) b128 writes; rest registers+DPP.
__device__ __forceinline__ void hs_step(
    const float* __restrict__ rbuf, float* __restrict__ wbuf,
    int fb, int rm, int r0, int rN, bool fullwb,
    float4* __restrict__ Mreg,
    const float2* __restrict__ ca, const float2* __restrict__ cb,
    const float2* __restrict__ cc, const float2* __restrict__ cd,
    const float2* __restrict__ ce)
{
    // boundary rows (only rows ever read from LDS; they are rewritten every step)
    float4 Mb0 = *(const float4*)(rbuf + STRIDE*rm + fb);
    float4 MbN = *(const float4*)(rbuf + STRIDE*rN + fb);

    float2 hu[RPT+2], hv[RPT+2];
    #pragma unroll
    for (int j = 0; j < RPT; ++j) hsum(Mreg[j], hu[j+1], hv[j+1]);
    hsum(Mb0, hu[0], hv[0]);
    hsum(MbN, hu[RPT+1], hv[RPT+1]);

    // vertical combine + coupled update + register carry; write only boundary-consumed rows
    #pragma unroll
    for (int j = 0; j < RPT; ++j) {
        float4 Mc = Mreg[j];
        float tux = fmaf(-4.f, Mc.x, fmaf(2.f, hu[j+1].x, hu[j].x) + hu[j+2].x);
        float tuy = fmaf(-4.f, Mc.z, fmaf(2.f, hu[j+1].y, hu[j].y) + hu[j+2].y);
        float tvx = fmaf(-4.f, Mc.y, fmaf(2.f, hv[j+1].x, hv[j].x) + hv[j+2].x);
        float tvy = fmaf(-4.f, Mc.w, fmaf(2.f, hv[j+1].y, hv[j].y) + hv[j+2].y);
        float2 un, vn;
        un.x = fmaf(ca[j].x, tux, -fmaf(cb[j].x, tvx, cc[j].x));
        un.y = fmaf(ca[j].y, tuy, -fmaf(cb[j].y, tvy, cc[j].y));
        vn.x = fmaf(cd[j].x, tvx, -fmaf(cb[j].x, tux, ce[j].x));
        vn.y = fmaf(cd[j].y, tvy, -fmaf(cb[j].y, tuy, ce[j].y));
        float4 nv = make_float4(un.x, vn.x, un.y, vn.y);
        Mreg[j] = nv;
        if (j == 0 || j == RPT-1 || fullwb)
            *(float4*)(wbuf + STRIDE*(r0 + j) + fb) = nv;
    }
}

__global__ __launch_bounds__(NTHR, 2)
void hs_mega(const float* __restrict__ x,     // (8,3,256,256): It, Ix, Iy
             const float* __restrict__ est,   // (8,2,256,256): u0, v0
             float* __restrict__ out,         // (8,2,256,256)
             float* __restrict__ ws)          // rings (double-buffered) + flags
{
    __shared__ __align__(16) float s0[LSZ];
    __shared__ __align__(16) float s1[LSZ];

    const int img = blockIdx.x, cs = blockIdx.y, rb = blockIdx.z;
    const int tid = threadIdx.x;
    const int er0 = rb*TILE_R - TT;
    const int ec0 = cs*TILE_C - TT;
    const int blin = (img*4 + cs)*8 + rb;      // 0..255
    unsigned* flags = (unsigned*)(ws + FLAG_OFS);

    // neighbor block id for the 8 poller threads (same image, 8-neighborhood)
    int nb = -1;
    if (tid < 8) {
        int t = (tid < 4) ? tid : tid + 1;     // skip (0,0)
        int dr = t/3 - 1, dc = t%3 - 1;
        int nrb = rb + dr, ncs = cs + dc;
        if (nrb >= 0 && nrb < 8 && ncs >= 0 && ncs < 4)
            nb = (img*4 + ncs)*8 + nrb;
    }

    // ---- per-thread sweep geometry: wave = row group, lane = colpair ----
    const int cp = tid & 63;           // 0..39 active
    const int rg = tid >> 6;           // 0..7
    const bool act = (cp < NCP);
    const int r0 = rg * RPT;
    const int fb = 4 + 4*cp;
    const int rm = (r0 == 0) ? 0 : r0 - 1;             // clamp: feeds d=0 ring only
    const int rN = (r0 + RPT > ER-1) ? ER-1 : r0+RPT;  // clamp: feeds d=0 ring only

    // ---- per-pixel update coefficients, computed ONCE, live in registers ----
    float2 ca[RPT], cb[RPT], cc[RPT], cd[RPT], ce[RPT];
    if (act) {
        const float* __restrict__ xit = x + img*3*PLANE;
        const float* __restrict__ xix = xit + PLANE;
        const float* __restrict__ xiy = xix + PLANE;
        #pragma unroll
        for (int i = 0; i < RPT; ++i) {
            int gr = er0 + r0 + i;
            #pragma unroll
            for (int j = 0; j < 2; ++j) {
                int gc = ec0 + 2*cp + j;
                float A=0.f, B=0.f, C=0.f, D=0.f, E=0.f;
                if (gr >= 0 && gr < HH && gc >= 0 && gc < WW) {
                    int q = gr*WW + gc;
                    float it = xit[q], ix = xix[q], iy = xiy[q];
                    float rd = 1.0f / (1.0f + ix*ix + iy*iy);
                    const float s12 = 1.0f/12.0f;
                    A = (1.0f - ix*ix*rd) * s12;
                    B = (ix*iy*rd) * s12;
                    C = ix*it*rd;
                    D = (1.0f - iy*iy*rd) * s12;
                    E = iy*it*rd;
                }
                if (j == 0) { ca[i].x=A; cb[i].x=B; cc[i].x=C; cd[i].x=D; ce[i].x=E; }
                else        { ca[i].y=A; cb[i].y=B; cc[i].y=C; cd[i].y=D; ce[i].y=E; }
            }
        }
    }

    // ---- initial full ext-tile stage from est (interleave on the fly; all 512 threads) ----
    {
        const float* __restrict__ eu = est + img*2*PLANE;
        const float* __restrict__ ev = eu + PLANE;
        for (int k = tid; k < ER*NCP; k += NTHR) {           // 1920 chunks
            int r = k / NCP, c = k - r*NCP;
            int gr = er0 + r, gc = ec0 + 2*c;
            float2 uu = make_float2(0.f,0.f), vv = make_float2(0.f,0.f);
            if (gr >= 0 && gr < HH && gc >= 0 && gc < WW) {
                uu = *(const float2*)(eu + gr*WW + gc);
                vv = *(const float2*)(ev + gr*WW + gc);
            }
            *(float4*)(s0 + 4 + STRIDE*r + 4*c) = make_float4(uu.x, vv.x, uu.y, vv.y);
        }
    }
    __syncthreads();

    // own-row center values live permanently in registers
    float4 Mreg[RPT];
    if (act) {
        #pragma unroll
        for (int j = 0; j < RPT; ++j)
            Mreg[j] = *(const float4*)(s0 + STRIDE*(r0 + j) + fb);
    }

    for (int p = 0; p < 13; ++p) {
        // ---- 8 (or 4) steps, 1 barrier each; full tile writeback only on the last ----
        if (p < 12) {
            #pragma unroll
            for (int q = 0; q < 4; ++q) {
                if (act) hs_step(s0, s1, fb, rm, r0, rN, false, Mreg, ca, cb, cc, cd, ce);
                __syncthreads();
                if (act) hs_step(s1, s0, fb, rm, r0, rN, (q == 3), Mreg, ca, cb, cc, cd, ce);
                __syncthreads();
            }
        } else {
            #pragma unroll
            for (int q = 0; q < 2; ++q) {
                if (act) hs_step(s0, s1, fb, rm, r0, rN, false, Mreg, ca, cb, cc, cd, ce);
                __syncthreads();
                if (act) hs_step(s1, s0, fb, rm, r0, rN, (q == 1), Mreg, ca, cb, cc, cd, ce);
                __syncthreads();
            }
        }
        // result (full tile, fullwb) now in s0

        if (p < 12) {
            float* ring = ws + (unsigned)(p & 1) * RING_OFS + img*RIMG;

            // ---- write depth-8 ring of inner tile (coherent 8B stores; all 512 threads) ----
            for (int k = tid; k < 640; k += NTHR) {
                int m = k; int r, c2;
                if (m < 256)      { r = m >> 5;              c2 = m & 31; }
                else if (m < 512) { r = 24 + ((m-256) >> 5); c2 = (m-256) & 31; }
                else { int mm = m - 512; r = 8 + (mm >> 3); int t = mm & 7; c2 = (t < 4) ? t : 24 + t; }
                const float* sp = s0 + 4 + STRIDE*(r + TT) + 4*(c2 + 4);  // ext col pair = c2+4
                float* gp = ring + ((rb*TILE_R + r)*(WW/2) + cs*(TILE_C/2) + c2)*4;
                __hip_atomic_store((ull*)gp,     *(const ull*)sp,       __ATOMIC_RELAXED, __HIP_MEMORY_SCOPE_AGENT);
                __hip_atomic_store((ull*)gp + 1, *(const ull*)(sp + 2), __ATOMIC_RELAXED, __HIP_MEMORY_SCOPE_AGENT);
            }
            asm volatile("s_waitcnt vmcnt(0)" ::: "memory");   // per-wave drain of ring stores
            __syncthreads();
            if (tid == 0)
                __hip_atomic_store(&flags[p*NBLK + blin], 0x5eed0100u + (unsigned)p,
                                   __ATOMIC_RELAXED, __HIP_MEMORY_SCOPE_AGENT);
            asm volatile("" ::: "memory");
            if (tid < 8 && nb >= 0) {
                const unsigned tgt = 0x5eed0100u + (unsigned)p;
                while (__hip_atomic_load(&flags[p*NBLK + nb],
                                         __ATOMIC_RELAXED, __HIP_MEMORY_SCOPE_AGENT) != tgt)
                    __builtin_amdgcn_s_sleep(1);
            }
            __syncthreads();

            // ---- restage ext halo ring from neighbors (coherent 8B loads) ----
            for (int k = tid; k < 896; k += NTHR) {
                int m = k; int r, c2;
                if (m < 320)      { r = m / 40;              c2 = m - (m/40)*40; }
                else if (m < 640) { int mm = m-320; r = 40 + mm/40; c2 = mm - (mm/40)*40; }
                else { int mm = m - 640; r = 8 + (mm >> 3); int t = mm & 7; c2 = (t < 4) ? t : 32 + t; }
                int gr = er0 + r, gc2 = cs*(TILE_C/2) - 4 + c2;
                ull v0 = 0, v1 = 0;
                if (gr >= 0 && gr < HH && gc2 >= 0 && gc2 < WW/2) {
                    const float* gp = ring + (gr*(WW/2) + gc2)*4;
                    v0 = __hip_atomic_load((const ull*)gp,     __ATOMIC_RELAXED, __HIP_MEMORY_SCOPE_AGENT);
                    v1 = __hip_atomic_load((const ull*)gp + 1, __ATOMIC_RELAXED, __HIP_MEMORY_SCOPE_AGENT);
                }
                float* sp = s0 + 4 + STRIDE*r + 4*c2;
                *(ull*)sp = v0;
                *(ull*)(sp + 2) = v1;
            }
            __syncthreads();

            // refresh carried centers ONLY where restage rewrote cells (halo rows/cols);
            // interior tile cells are stale in LDS (by design) but live in Mreg.
            if (act) {
                #pragma unroll
                for (int j = 0; j < RPT; ++j) {
                    int r = r0 + j;
                    if (r < TT || r >= ER-TT || cp < 4 || cp >= NCP-4)
                        Mreg[j] = *(const float4*)(s0 + STRIDE*r + fb);
                }
            }
        }
    }

    // ---- final: de-interleave inner tile to planar out (full tile fresh via fullwb) ----
    {
        float* ou = out + img*2*PLANE;
        float* ov = ou + PLANE;
        for (int k = tid; k < 1024; k += NTHR) {
            int r = k >> 5, c2 = k & 31;
            float4 V = *(const float4*)(s0 + 4 + STRIDE*(r + TT) + 4*(c2 + 4));
            int q = (rb*TILE_R + r)*WW + cs*TILE_C + 2*c2;
            *(float2*)(ou + q) = make_float2(V.x, V.z);
            *(float2*)(ov + q) = make_float2(V.y, V.w);
        }
    }
}

extern "C" void kernel_launch(void* const* d_in, const int* in_sizes, int n_in,
                              void* d_out, int out_size, void* d_ws, size_t ws_size,
                              hipStream_t stream) {
    const float* x   = (const float*)d_in[0];   // (8,3,256,256) fp32
    const float* est = (const float*)d_in[1];   // (8,2,256,256) fp32
    float* out = (float*)d_out;
    float* ws  = (float*)d_ws;                  // ring slot0 @0, slot1 @8MB, flags @16MB
                                                // flags 0xAA-poisoned each launch: != MAGIC, no reset needed

    dim3 grid(8, WW/TILE_C, HH/TILE_R);         // 256 blocks, all co-resident (1/CU: 63KB LDS, 8 waves)
    dim3 blk(NTHR);
    hs_mega<<<grid, blk, 0, stream>>>(x, est, out, ws);
}

// Round 4
// 174.460 us; speedup vs baseline: 1.1418x; 1.0218x over previous
//
#include <hip/hip_runtime.h>

typedef unsigned long long ull;

#define HH 256
#define WW 256
#define PLANE (HH*WW)
#define TILE_R 32
#define TILE_C 64
#define TT 8
#define ER (TILE_R + 2*TT)   // 48 ext rows
#define EC (TILE_C + 2*TT)   // 80 ext cols
#define NCP (EC/2)           // 40 col-pairs per row
#define NRG 16               // row groups = waves (wave w owns rows w*RPT..w*RPT+2, lanes 0..39 = colpair)
#define RPT (ER/NRG)         // 3 rows per thread
#define NTHR 1024            // 16 waves (4/SIMD); lanes 40..63 idle in compute, active in staging loops
#define STRIDE 164           // row stride in floats, 16B-aligned
#define LSZ (4 + ER*STRIDE + 4)   // front pad + tile + end pad (~31.5 KB/buffer)

#define RING_OFS (2u*1024u*1024u)   // float offset of ring slot 1 (8 MB)
#define FLAG_OFS (4u*1024u*1024u)   // float offset of flag array (16 MB)
#define RIMG (HH*(WW/2)*4)          // floats per interleaved ring image (131072)
#define NBLK 256

// DPP cross-lane: VALU pipe, replaces LDS L/R edge reads.
// wave_shr:1 (0x138): lane n receives lane n-1. wave_shl:1 (0x130): lane n receives lane n+1.
// bound_ctrl=true: out-of-range / EXEC-disabled source lanes give 0 -> lands only on ext-edge
// columns (ring-0, decays before each exchange).
__device__ __forceinline__ float dpp_prev(float v) {
    return __int_as_float(__builtin_amdgcn_update_dpp(0, __float_as_int(v), 0x138, 0xF, 0xF, true));
}
__device__ __forceinline__ float dpp_next(float v) {
    return __int_as_float(__builtin_amdgcn_update_dpp(0, __float_as_int(v), 0x130, 0xF, 0xF, true));
}

// horizontal [1,2,1] sums for one row held in a float4 (u0,v0,u1,v1); L/R via DPP.
__device__ __forceinline__ void hsum(const float4 M, float2& hu, float2& hv) {
    float Lz = dpp_prev(M.z), Lw = dpp_prev(M.w);
    float Rx = dpp_next(M.x), Ry = dpp_next(M.y);
    hu = make_float2(fmaf(2.f, M.x, Lz) + M.z, fmaf(2.f, M.z, M.x) + Rx);
    hv = make_float2(fmaf(2.f, M.y, Lw) + M.w, fmaf(2.f, M.w, M.y) + Ry);
}

// one Jacobi step: LDS = 2 b128 boundary reads + 2 (or RPT on fullwb) b128 writes; rest registers+DPP.
__device__ __forceinline__ void hs_step(
    const float* __restrict__ rbuf, float* __restrict__ wbuf,
    int fb, int rm, int r0, int rN, bool fullwb,
    float4* __restrict__ Mreg,
    const float2* __restrict__ ca, const float2* __restrict__ cb,
    const float2* __restrict__ cc, const float2* __restrict__ cd,
    const float2* __restrict__ ce)
{
    // boundary rows (only rows ever read from LDS; they are rewritten every step)
    float4 Mb0 = *(const float4*)(rbuf + STRIDE*rm + fb);
    float4 MbN = *(const float4*)(rbuf + STRIDE*rN + fb);

    float2 hu[RPT+2], hv[RPT+2];
    #pragma unroll
    for (int j = 0; j < RPT; ++j) hsum(Mreg[j], hu[j+1], hv[j+1]);
    hsum(Mb0, hu[0], hv[0]);
    hsum(MbN, hu[RPT+1], hv[RPT+1]);

    // vertical combine + coupled update + register carry; write only boundary-consumed rows
    #pragma unroll
    for (int j = 0; j < RPT; ++j) {
        float4 Mc = Mreg[j];
        float tux = fmaf(-4.f, Mc.x, fmaf(2.f, hu[j+1].x, hu[j].x) + hu[j+2].x);
        float tuy = fmaf(-4.f, Mc.z, fmaf(2.f, hu[j+1].y, hu[j].y) + hu[j+2].y);
        float tvx = fmaf(-4.f, Mc.y, fmaf(2.f, hv[j+1].x, hv[j].x) + hv[j+2].x);
        float tvy = fmaf(-4.f, Mc.w, fmaf(2.f, hv[j+1].y, hv[j].y) + hv[j+2].y);
        float2 un, vn;
        un.x = fmaf(ca[j].x, tux, -fmaf(cb[j].x, tvx, cc[j].x));
        un.y = fmaf(ca[j].y, tuy, -fmaf(cb[j].y, tvy, cc[j].y));
        vn.x = fmaf(cd[j].x, tvx, -fmaf(cb[j].x, tux, ce[j].x));
        vn.y = fmaf(cd[j].y, tvy, -fmaf(cb[j].y, tuy, ce[j].y));
        float4 nv = make_float4(un.x, vn.x, un.y, vn.y);
        Mreg[j] = nv;
        if (j == 0 || j == RPT-1 || fullwb)
            *(float4*)(wbuf + STRIDE*(r0 + j) + fb) = nv;
    }
}

// 16 waves/block, 1 block/CU (grid=256): __launch_bounds__(1024,4) caps VGPR at 128.
__global__ __launch_bounds__(NTHR, 4)
void hs_mega(const float* __restrict__ x,     // (8,3,256,256): It, Ix, Iy
             const float* __restrict__ est,   // (8,2,256,256): u0, v0
             float* __restrict__ out,         // (8,2,256,256)
             float* __restrict__ ws)          // rings (double-buffered) + flags
{
    __shared__ __align__(16) float s0[LSZ];
    __shared__ __align__(16) float s1[LSZ];

    const int img = blockIdx.x, cs = blockIdx.y, rb = blockIdx.z;
    const int tid = threadIdx.x;
    const int er0 = rb*TILE_R - TT;
    const int ec0 = cs*TILE_C - TT;
    const int blin = (img*4 + cs)*8 + rb;      // 0..255
    unsigned* flags = (unsigned*)(ws + FLAG_OFS);

    // neighbor block id for the 8 poller threads (same image, 8-neighborhood)
    int nb = -1;
    if (tid < 8) {
        int t = (tid < 4) ? tid : tid + 1;     // skip (0,0)
        int dr = t/3 - 1, dc = t%3 - 1;
        int nrb = rb + dr, ncs = cs + dc;
        if (nrb >= 0 && nrb < 8 && ncs >= 0 && ncs < 4)
            nb = (img*4 + ncs)*8 + nrb;
    }

    // ---- per-thread sweep geometry: wave = row group, lane = colpair ----
    const int cp = tid & 63;           // 0..39 active
    const int rg = tid >> 6;           // 0..15
    const bool act = (cp < NCP);
    const int r0 = rg * RPT;
    const int fb = 4 + 4*cp;
    const int rm = (r0 == 0) ? 0 : r0 - 1;             // clamp: feeds d=0 ring only
    const int rN = (r0 + RPT > ER-1) ? ER-1 : r0+RPT;  // clamp: feeds d=0 ring only

    // ---- per-pixel update coefficients, computed ONCE, live in registers ----
    float2 ca[RPT], cb[RPT], cc[RPT], cd[RPT], ce[RPT];
    if (act) {
        const float* __restrict__ xit = x + img*3*PLANE;
        const float* __restrict__ xix = xit + PLANE;
        const float* __restrict__ xiy = xix + PLANE;
        #pragma unroll
        for (int i = 0; i < RPT; ++i) {
            int gr = er0 + r0 + i;
            #pragma unroll
            for (int j = 0; j < 2; ++j) {
                int gc = ec0 + 2*cp + j;
                float A=0.f, B=0.f, C=0.f, D=0.f, E=0.f;
                if (gr >= 0 && gr < HH && gc >= 0 && gc < WW) {
                    int q = gr*WW + gc;
                    float it = xit[q], ix = xix[q], iy = xiy[q];
                    float rd = 1.0f / (1.0f + ix*ix + iy*iy);
                    const float s12 = 1.0f/12.0f;
                    A = (1.0f - ix*ix*rd) * s12;
                    B = (ix*iy*rd) * s12;
                    C = ix*it*rd;
                    D = (1.0f - iy*iy*rd) * s12;
                    E = iy*it*rd;
                }
                if (j == 0) { ca[i].x=A; cb[i].x=B; cc[i].x=C; cd[i].x=D; ce[i].x=E; }
                else        { ca[i].y=A; cb[i].y=B; cc[i].y=C; cd[i].y=D; ce[i].y=E; }
            }
        }
    }

    // ---- initial full ext-tile stage from est (interleave on the fly; all 1024 threads) ----
    {
        const float* __restrict__ eu = est + img*2*PLANE;
        const float* __restrict__ ev = eu + PLANE;
        for (int k = tid; k < ER*NCP; k += NTHR) {           // 1920 chunks, 2 strides
            int r = k / NCP, c = k - r*NCP;
            int gr = er0 + r, gc = ec0 + 2*c;
            float2 uu = make_float2(0.f,0.f), vv = make_float2(0.f,0.f);
            if (gr >= 0 && gr < HH && gc >= 0 && gc < WW) {
                uu = *(const float2*)(eu + gr*WW + gc);
                vv = *(const float2*)(ev + gr*WW + gc);
            }
            *(float4*)(s0 + 4 + STRIDE*r + 4*c) = make_float4(uu.x, vv.x, uu.y, vv.y);
        }
    }
    __syncthreads();

    // own-row center values live permanently in registers
    float4 Mreg[RPT];
    if (act) {
        #pragma unroll
        for (int j = 0; j < RPT; ++j)
            Mreg[j] = *(const float4*)(s0 + STRIDE*(r0 + j) + fb);
    }

    for (int p = 0; p < 13; ++p) {
        // ---- 8 (or 4) steps, 1 barrier each; full tile writeback only on the last ----
        if (p < 12) {
            #pragma unroll
            for (int q = 0; q < 4; ++q) {
                if (act) hs_step(s0, s1, fb, rm, r0, rN, false, Mreg, ca, cb, cc, cd, ce);
                __syncthreads();
                if (act) hs_step(s1, s0, fb, rm, r0, rN, (q == 3), Mreg, ca, cb, cc, cd, ce);
                __syncthreads();
            }
        } else {
            #pragma unroll
            for (int q = 0; q < 2; ++q) {
                if (act) hs_step(s0, s1, fb, rm, r0, rN, false, Mreg, ca, cb, cc, cd, ce);
                __syncthreads();
                if (act) hs_step(s1, s0, fb, rm, r0, rN, (q == 1), Mreg, ca, cb, cc, cd, ce);
                __syncthreads();
            }
        }
        // result (full tile, fullwb) now in s0

        if (p < 12) {
            float* ring = ws + (unsigned)(p & 1) * RING_OFS + img*RIMG;

            // ---- write depth-8 ring of inner tile (coherent 8B stores) ----
            for (int k = tid; k < 640; k += NTHR) {
                int m = k; int r, c2;
                if (m < 256)      { r = m >> 5;              c2 = m & 31; }
                else if (m < 512) { r = 24 + ((m-256) >> 5); c2 = (m-256) & 31; }
                else { int mm = m - 512; r = 8 + (mm >> 3); int t = mm & 7; c2 = (t < 4) ? t : 24 + t; }
                const float* sp = s0 + 4 + STRIDE*(r + TT) + 4*(c2 + 4);  // ext col pair = c2+4
                float* gp = ring + ((rb*TILE_R + r)*(WW/2) + cs*(TILE_C/2) + c2)*4;
                __hip_atomic_store((ull*)gp,     *(const ull*)sp,       __ATOMIC_RELAXED, __HIP_MEMORY_SCOPE_AGENT);
                __hip_atomic_store((ull*)gp + 1, *(const ull*)(sp + 2), __ATOMIC_RELAXED, __HIP_MEMORY_SCOPE_AGENT);
            }
            asm volatile("s_waitcnt vmcnt(0)" ::: "memory");   // per-wave drain of ring stores
            __syncthreads();
            if (tid == 0)
                __hip_atomic_store(&flags[p*NBLK + blin], 0x5eed0100u + (unsigned)p,
                                   __ATOMIC_RELAXED, __HIP_MEMORY_SCOPE_AGENT);
            asm volatile("" ::: "memory");
            if (tid < 8 && nb >= 0) {
                const unsigned tgt = 0x5eed0100u + (unsigned)p;
                while (__hip_atomic_load(&flags[p*NBLK + nb],
                                         __ATOMIC_RELAXED, __HIP_MEMORY_SCOPE_AGENT) != tgt)
                    __builtin_amdgcn_s_sleep(1);
            }
            __syncthreads();

            // ---- restage ext halo ring from neighbors (coherent 8B loads) ----
            for (int k = tid; k < 896; k += NTHR) {
                int m = k; int r, c2;
                if (m < 320)      { r = m / 40;              c2 = m - (m/40)*40; }
                else if (m < 640) { int mm = m-320; r = 40 + mm/40; c2 = mm - (mm/40)*40; }
                else { int mm = m - 640; r = 8 + (mm >> 3); int t = mm & 7; c2 = (t < 4) ? t : 32 + t; }
                int gr = er0 + r, gc2 = cs*(TILE_C/2) - 4 + c2;
                ull v0 = 0, v1 = 0;
                if (gr >= 0 && gr < HH && gc2 >= 0 && gc2 < WW/2) {
                    const float* gp = ring + (gr*(WW/2) + gc2)*4;
                    v0 = __hip_atomic_load((const ull*)gp,     __ATOMIC_RELAXED, __HIP_MEMORY_SCOPE_AGENT);
                    v1 = __hip_atomic_load((const ull*)gp + 1, __ATOMIC_RELAXED, __HIP_MEMORY_SCOPE_AGENT);
                }
                float* sp = s0 + 4 + STRIDE*r + 4*c2;
                *(ull*)sp = v0;
                *(ull*)(sp + 2) = v1;
            }
            __syncthreads();

            // refresh carried centers ONLY where restage rewrote cells (halo rows/cols);
            // interior tile cells are stale in LDS (by design) but live in Mreg.
            if (act) {
                #pragma unroll
                for (int j = 0; j < RPT; ++j) {
                    int r = r0 + j;
                    if (r < TT || r >= ER-TT || cp < 4 || cp >= NCP-4)
                        Mreg[j] = *(const float4*)(s0 + STRIDE*r + fb);
                }
            }
        }
    }

    // ---- final: de-interleave inner tile to planar out (full tile fresh via fullwb) ----
    {
        float* ou = out + img*2*PLANE;
        float* ov = ou + PLANE;
        for (int k = tid; k < 1024; k += NTHR) {
            int r = k >> 5, c2 = k & 31;
            float4 V = *(const float4*)(s0 + 4 + STRIDE*(r + TT) + 4*(c2 + 4));
            int q = (rb*TILE_R + r)*WW + cs*TILE_C + 2*c2;
            *(float2*)(ou + q) = make_float2(V.x, V.z);
            *(float2*)(ov + q) = make_float2(V.y, V.w);
        }
    }
}

extern "C" void kernel_launch(void* const* d_in, const int* in_sizes, int n_in,
                              void* d_out, int out_size, void* d_ws, size_t ws_size,
                              hipStream_t stream) {
    const float* x   = (const float*)d_in[0];   // (8,3,256,256) fp32
    const float* est = (const float*)d_in[1];   // (8,2,256,256) fp32
    float* out = (float*)d_out;
    float* ws  = (float*)d_ws;                  // ring slot0 @0, slot1 @8MB, flags @16MB
                                                // flags 0xAA-poisoned each launch: != MAGIC, no reset needed

    dim3 grid(8, WW/TILE_C, HH/TILE_R);         // 256 blocks, all co-resident (1/CU: 63KB LDS, 16 waves)
    dim3 blk(NTHR);
    hs_mega<<<grid, blk, 0, stream>>>(x, est, out, ws);
}

// Round 5
// 167.475 us; speedup vs baseline: 1.1894x; 1.0417x over previous
//
#include <hip/hip_runtime.h>

typedef unsigned long long ull;
typedef float f32x2 __attribute__((ext_vector_type(2)));
#define FMA2(a,b,c) __builtin_elementwise_fma((a),(b),(c))

#define HH 256
#define WW 256
#define PLANE (HH*WW)
#define TILE_R 32
#define TILE_C 64
#define TT 8
#define ER (TILE_R + 2*TT)   // 48 ext rows
#define EC (TILE_C + 2*TT)   // 80 ext cols
#define NCP (EC/2)           // 40 col-pairs per row
#define NRG 16               // row groups = waves (wave w owns rows w*RPT..w*RPT+2, lanes 0..39 = colpair)
#define RPT (ER/NRG)         // 3 rows per thread
#define NTHR 1024            // 16 waves (4/SIMD); lanes 40..63 idle in compute, active in staging loops
#define STRIDE 164           // row stride in floats, 16B-aligned
#define LSZ (4 + ER*STRIDE + 4)   // front pad + tile + end pad (~31.5 KB/buffer)

#define RING_OFS (2u*1024u*1024u)   // float offset of ring slot 1 (8 MB)
#define FLAG_OFS (4u*1024u*1024u)   // float offset of flag array (16 MB)
#define RIMG (HH*(WW/2)*4)          // floats per interleaved ring image (131072)
#define NBLK 256

// DPP cross-lane: VALU pipe, replaces LDS L/R edge reads.
// wave_shr:1 (0x138): lane n receives lane n-1. wave_shl:1 (0x130): lane n receives lane n+1.
// bound_ctrl=true: out-of-range / EXEC-disabled source lanes give 0 -> lands only on ext-edge
// columns (ring-0, decays before each exchange).
__device__ __forceinline__ float dpp_prev(float v) {
    return __int_as_float(__builtin_amdgcn_update_dpp(0, __float_as_int(v), 0x138, 0xF, 0xF, true));
}
__device__ __forceinline__ float dpp_next(float v) {
    return __int_as_float(__builtin_amdgcn_update_dpp(0, __float_as_int(v), 0x130, 0xF, 0xF, true));
}

// horizontal [1,2,1] sums for one row float4 (u0,v0,u1,v1), u/v packed as f32x2 (v_pk_fma_f32).
// S0 = sums at col-pair pos 0 (u0,v0); S1 = pos 1 (u1,v1). Same op order as scalar version.
__device__ __forceinline__ void hsum2(const float4 M, f32x2& S0, f32x2& S1) {
    f32x2 lo = { M.x, M.y }, hi = { M.z, M.w };
    f32x2 DL = { dpp_prev(M.z), dpp_prev(M.w) };   // left pair's (u1,v1)
    f32x2 DR = { dpp_next(M.x), dpp_next(M.y) };   // right pair's (u0,v0)
    const f32x2 two = 2.0f;
    S0 = FMA2(two, lo, DL) + hi;
    S1 = FMA2(two, hi, lo) + DR;
}

// one Jacobi step: LDS = 2 b128 boundary reads + 2 (or RPT on fullwb) b128 writes;
// math in packed-f32 (v_pk_fma_f32), DPP for horizontal neighbors.
// Coeffs per row j, pos s: CA=(A,D), CB=(B,B), CC=(C,E) so that
// (un,vn) = CA*(tu,tv) - (CB*(tv,tu) + CC)  [swap via .yx -> op_sel, free].
__device__ __forceinline__ void hs_step(
    const float* __restrict__ rbuf, float* __restrict__ wbuf,
    int fb, int rm, int rw0, int rN, bool fullwb,
    float4* __restrict__ Mreg,
    const f32x2 (* __restrict__ CA)[2], const f32x2 (* __restrict__ CB)[2],
    const f32x2 (* __restrict__ CC)[2])
{
    // boundary rows (only rows ever read from LDS; they are rewritten every step)
    float4 Mb0 = *(const float4*)(rbuf + STRIDE*rm + fb);
    float4 MbN = *(const float4*)(rbuf + STRIDE*rN + fb);

    f32x2 S0[RPT+2], S1[RPT+2];
    #pragma unroll
    for (int j = 0; j < RPT; ++j) hsum2(Mreg[j], S0[j+1], S1[j+1]);
    hsum2(Mb0, S0[0], S1[0]);
    hsum2(MbN, S0[RPT+1], S1[RPT+1]);

    const f32x2 two = 2.0f, m4 = -4.0f;
    #pragma unroll
    for (int j = 0; j < RPT; ++j) {
        float4 Mc = Mreg[j];
        f32x2 Mlo = { Mc.x, Mc.y }, Mhi = { Mc.z, Mc.w };
        f32x2 T0 = FMA2(m4, Mlo, FMA2(two, S0[j+1], S0[j]) + S0[j+2]);   // (tu,tv) pos0
        f32x2 T1 = FMA2(m4, Mhi, FMA2(two, S1[j+1], S1[j]) + S1[j+2]);   // (tu,tv) pos1
        f32x2 rr0 = FMA2(CA[j][0], T0, -FMA2(CB[j][0], T0.yx, CC[j][0]));
        f32x2 rr1 = FMA2(CA[j][1], T1, -FMA2(CB[j][1], T1.yx, CC[j][1]));
        float4 nv = make_float4(rr0.x, rr0.y, rr1.x, rr1.y);
        Mreg[j] = nv;
        if (j == 0 || j == RPT-1 || fullwb)
            *(float4*)(wbuf + STRIDE*(rw0 + j) + fb) = nv;
    }
}

// 16 waves/block, 1 block/CU (grid=256): __launch_bounds__(1024,4) caps VGPR at 128.
__global__ __launch_bounds__(NTHR, 4)
void hs_mega(const float* __restrict__ x,     // (8,3,256,256): It, Ix, Iy
             const float* __restrict__ est,   // (8,2,256,256): u0, v0
             float* __restrict__ out,         // (8,2,256,256)
             float* __restrict__ ws)          // rings (double-buffered) + flags
{
    __shared__ __align__(16) float s0[LSZ];
    __shared__ __align__(16) float s1[LSZ];

    const int img = blockIdx.x, cs = blockIdx.y, rb = blockIdx.z;
    const int tid = threadIdx.x;
    const int er0 = rb*TILE_R - TT;
    const int ec0 = cs*TILE_C - TT;
    const int blin = (img*4 + cs)*8 + rb;      // 0..255
    unsigned* flags = (unsigned*)(ws + FLAG_OFS);

    // neighbor block id for the 8 poller threads (same image, 8-neighborhood)
    int nb = -1;
    if (tid < 8) {
        int t = (tid < 4) ? tid : tid + 1;     // skip (0,0)
        int dr = t/3 - 1, dc = t%3 - 1;
        int nrb = rb + dr, ncs = cs + dc;
        if (nrb >= 0 && nrb < 8 && ncs >= 0 && ncs < 4)
            nb = (img*4 + ncs)*8 + nrb;
    }

    // ---- per-thread sweep geometry: wave = row group, lane = colpair ----
    const int cp = tid & 63;           // 0..39 active
    const int rg = tid >> 6;           // 0..15
    const bool act = (cp < NCP);
    const int r0 = rg * RPT;
    const int fb = 4 + 4*cp;
    const int rm = (r0 == 0) ? 0 : r0 - 1;             // clamp: feeds d=0 ring only
    const int rN = (r0 + RPT > ER-1) ? ER-1 : r0+RPT;  // clamp: feeds d=0 ring only

    // ---- per-pixel update coefficients, computed ONCE, packed for v_pk math ----
    // OOB pixels: all-zero coeffs -> update writes exact 0 -> matches reference zero-pad.
    f32x2 CA[RPT][2], CB[RPT][2], CC[RPT][2];
    if (act) {
        const float* __restrict__ xit = x + img*3*PLANE;
        const float* __restrict__ xix = xit + PLANE;
        const float* __restrict__ xiy = xix + PLANE;
        #pragma unroll
        for (int i = 0; i < RPT; ++i) {
            int gr = er0 + r0 + i;
            #pragma unroll
            for (int j = 0; j < 2; ++j) {
                int gc = ec0 + 2*cp + j;
                float A=0.f, B=0.f, C=0.f, D=0.f, E=0.f;
                if (gr >= 0 && gr < HH && gc >= 0 && gc < WW) {
                    int q = gr*WW + gc;
                    float it = xit[q], ix = xix[q], iy = xiy[q];
                    float rd = 1.0f / (1.0f + ix*ix + iy*iy);
                    const float s12 = 1.0f/12.0f;
                    A = (1.0f - ix*ix*rd) * s12;
                    B = (ix*iy*rd) * s12;
                    C = ix*it*rd;
                    D = (1.0f - iy*iy*rd) * s12;
                    E = iy*it*rd;
                }
                CA[i][j] = (f32x2){ A, D };
                CB[i][j] = (f32x2){ B, B };
                CC[i][j] = (f32x2){ C, E };
            }
        }
    }

    // ---- initial full ext-tile stage from est (interleave on the fly; all 1024 threads) ----
    {
        const float* __restrict__ eu = est + img*2*PLANE;
        const float* __restrict__ ev = eu + PLANE;
        for (int k = tid; k < ER*NCP; k += NTHR) {           // 1920 chunks, 2 strides
            int r = k / NCP, c = k - r*NCP;
            int gr = er0 + r, gc = ec0 + 2*c;
            float2 uu = make_float2(0.f,0.f), vv = make_float2(0.f,0.f);
            if (gr >= 0 && gr < HH && gc >= 0 && gc < WW) {
                uu = *(const float2*)(eu + gr*WW + gc);
                vv = *(const float2*)(ev + gr*WW + gc);
            }
            *(float4*)(s0 + 4 + STRIDE*r + 4*c) = make_float4(uu.x, vv.x, uu.y, vv.y);
        }
    }
    __syncthreads();

    // own-row center values live permanently in registers
    float4 Mreg[RPT];
    if (act) {
        #pragma unroll
        for (int j = 0; j < RPT; ++j)
            Mreg[j] = *(const float4*)(s0 + STRIDE*(r0 + j) + fb);
    }

    for (int p = 0; p < 13; ++p) {
        // ---- 8 (or 4) steps, 1 barrier each; full tile writeback only on the last ----
        if (p < 12) {
            #pragma unroll
            for (int q = 0; q < 4; ++q) {
                if (act) hs_step(s0, s1, fb, rm, r0, rN, false, Mreg, CA, CB, CC);
                __syncthreads();
                if (act) hs_step(s1, s0, fb, rm, r0, rN, (q == 3), Mreg, CA, CB, CC);
                __syncthreads();
            }
        } else {
            #pragma unroll
            for (int q = 0; q < 2; ++q) {
                if (act) hs_step(s0, s1, fb, rm, r0, rN, false, Mreg, CA, CB, CC);
                __syncthreads();
                if (act) hs_step(s1, s0, fb, rm, r0, rN, (q == 1), Mreg, CA, CB, CC);
                __syncthreads();
            }
        }
        // result (full tile, fullwb) now in s0

        if (p < 12) {
            float* ring = ws + (unsigned)(p & 1) * RING_OFS + img*RIMG;

            // ---- write depth-8 ring of inner tile (coherent 8B stores) ----
            for (int k = tid; k < 640; k += NTHR) {
                int m = k; int r, c2;
                if (m < 256)      { r = m >> 5;              c2 = m & 31; }
                else if (m < 512) { r = 24 + ((m-256) >> 5); c2 = (m-256) & 31; }
                else { int mm = m - 512; r = 8 + (mm >> 3); int t = mm & 7; c2 = (t < 4) ? t : 24 + t; }
                const float* sp = s0 + 4 + STRIDE*(r + TT) + 4*(c2 + 4);  // ext col pair = c2+4
                float* gp = ring + ((rb*TILE_R + r)*(WW/2) + cs*(TILE_C/2) + c2)*4;
                __hip_atomic_store((ull*)gp,     *(const ull*)sp,       __ATOMIC_RELAXED, __HIP_MEMORY_SCOPE_AGENT);
                __hip_atomic_store((ull*)gp + 1, *(const ull*)(sp + 2), __ATOMIC_RELAXED, __HIP_MEMORY_SCOPE_AGENT);
            }
            asm volatile("s_waitcnt vmcnt(0)" ::: "memory");   // per-wave drain of ring stores
            __syncthreads();
            if (tid == 0)
                __hip_atomic_store(&flags[p*NBLK + blin], 0x5eed0100u + (unsigned)p,
                                   __ATOMIC_RELAXED, __HIP_MEMORY_SCOPE_AGENT);
            asm volatile("" ::: "memory");
            if (tid < 8 && nb >= 0) {
                const unsigned tgt = 0x5eed0100u + (unsigned)p;
                while (__hip_atomic_load(&flags[p*NBLK + nb],
                                         __ATOMIC_RELAXED, __HIP_MEMORY_SCOPE_AGENT) != tgt)
                    __builtin_amdgcn_s_sleep(1);
            }
            __syncthreads();

            // ---- restage ext halo ring from neighbors (coherent 8B loads) ----
            for (int k = tid; k < 896; k += NTHR) {
                int m = k; int r, c2;
                if (m < 320)      { r = m / 40;              c2 = m - (m/40)*40; }
                else if (m < 640) { int mm = m-320; r = 40 + mm/40; c2 = mm - (mm/40)*40; }
                else { int mm = m - 640; r = 8 + (mm >> 3); int t = mm & 7; c2 = (t < 4) ? t : 32 + t; }
                int gr = er0 + r, gc2 = cs*(TILE_C/2) - 4 + c2;
                ull v0 = 0, v1 = 0;
                if (gr >= 0 && gr < HH && gc2 >= 0 && gc2 < WW/2) {
                    const float* gp = ring + (gr*(WW/2) + gc2)*4;
                    v0 = __hip_atomic_load((const ull*)gp,     __ATOMIC_RELAXED, __HIP_MEMORY_SCOPE_AGENT);
                    v1 = __hip_atomic_load((const ull*)gp + 1, __ATOMIC_RELAXED, __HIP_MEMORY_SCOPE_AGENT);
                }
                float* sp = s0 + 4 + STRIDE*r + 4*c2;
                *(ull*)sp = v0;
                *(ull*)(sp + 2) = v1;
            }
            __syncthreads();

            // refresh carried centers ONLY where restage rewrote cells (halo rows/cols);
            // interior tile cells are stale in LDS (by design) but live in Mreg.
            if (act) {
                #pragma unroll
                for (int j = 0; j < RPT; ++j) {
                    int r = r0 + j;
                    if (r < TT || r >= ER-TT || cp < 4 || cp >= NCP-4)
                        Mreg[j] = *(const float4*)(s0 + STRIDE*r + fb);
                }
            }
        }
    }

    // ---- final: de-interleave inner tile to planar out (full tile fresh via fullwb) ----
    {
        float* ou = out + img*2*PLANE;
        float* ov = ou + PLANE;
        for (int k = tid; k < 1024; k += NTHR) {
            int r = k >> 5, c2 = k & 31;
            float4 V = *(const float4*)(s0 + 4 + STRIDE*(r + TT) + 4*(c2 + 4));
            int q = (rb*TILE_R + r)*WW + cs*TILE_C + 2*c2;
            *(float2*)(ou + q) = make_float2(V.x, V.z);
            *(float2*)(ov + q) = make_float2(V.y, V.w);
        }
    }
}

extern "C" void kernel_launch(void* const* d_in, const int* in_sizes, int n_in,
                              void* d_out, int out_size, void* d_ws, size_t ws_size,
                              hipStream_t stream) {
    const float* x   = (const float*)d_in[0];   // (8,3,256,256) fp32
    const float* est = (const float*)d_in[1];   // (8,2,256,256) fp32
    float* out = (float*)d_out;
    float* ws  = (float*)d_ws;                  // ring slot0 @0, slot1 @8MB, flags @16MB
                                                // flags 0xAA-poisoned each launch: != MAGIC, no reset needed

    dim3 grid(8, WW/TILE_C, HH/TILE_R);         // 256 blocks, all co-resident (1/CU: 63KB LDS, 16 waves)
    dim3 blk(NTHR);
    hs_mega<<<grid, blk, 0, stream>>>(x, est, out, ws);
}